// Round 14
// baseline (270.075 us; speedup 1.0000x reference)
//
#include <hip/hip_runtime.h>
#include <math.h>

#define BB 4
#define CC 64
#define HH 128
#define WW 128
#define HWP 16384

typedef _Float16 h2 __attribute__((ext_vector_type(2)));
typedef _Float16 h4 __attribute__((ext_vector_type(4)));
typedef __fp16  p2 __attribute__((ext_vector_type(2)));   // cvt_pkrtz's return type
typedef float f32x4 __attribute__((ext_vector_type(4)));
union HU { unsigned u; h2 h; p2 p; };
union U2H { uint2 u; h4 h; };
static __device__ __forceinline__ h2 u2h(unsigned x){ HU v; v.u = x; return v.h; }
static __device__ __forceinline__ unsigned h2u(h2 x){ HU v; v.h = x; return v.u; }
static __device__ __forceinline__ unsigned pk2u(float a, float b){
    HU v; v.p = __builtin_amdgcn_cvt_pkrtz(a, b); return v.u;
}

// ---------------- kT: build f13t[b][y][x][64 pairs u32] (f16 channel pairs).
// pairs 0..31 = f1 channels (2cp,2cp+1); pairs 32..63 = f3 channels.
__global__ __launch_bounds__(256) void kT(
    const float* __restrict__ f1, const float* __restrict__ f3,
    unsigned* __restrict__ f13t)
{
    __shared__ float lt[64*129];
    int b = blockIdx.x >> 7, y = blockIdx.x & 127;
    int t = threadIdx.x;
    unsigned* dst = f13t + ((size_t)((b << 14) + (y << 7)))*64;
    for (int half = 0; half < 2; ++half) {
        const float* src = (half == 0 ? f1 : f3) + (((size_t)b*64) << 14) + (y << 7);
#pragma unroll 4
        for (int i = 0; i < 32; ++i) {
            int idx = i*256 + t; int c = idx >> 7, x = idx & 127;
            lt[c*129 + x] = src[(c << 14) + x];
        }
        __syncthreads();
#pragma unroll 4
        for (int i = 0; i < 16; ++i) {
            int idx = i*256 + t; int x = idx >> 5, cp = idx & 31;
            dst[x*64 + half*32 + cp] = pk2u(lt[(2*cp)*129 + x], lt[(2*cp+1)*129 + x]);
        }
        __syncthreads();
    }
}

// ---------------- K0: pack weights into MFMA A-fragments; zero stats.
// wmf (k2): u32 idx ((r*64+l)*36+kb)*2+j; P = kb*8+(l>>4)*2+j, kt = P>>5,
//   cp = P&31 (f1 pairs); out-ch r*16+(l&15).
// wof (k1): u32 idx ((mt*64+l)*72+kb)*2+j; P = kb*8+(l>>4)*2+j in [0,576);
//   kt = P>>6, cp = P&63 (concat pair); och = mt*16+(l&15), zero if och>=27.
__global__ __launch_bounds__(256) void k0_wt(
    const float* __restrict__ ow, const float* __restrict__ mw,
    unsigned* __restrict__ wmf, unsigned* __restrict__ wof,
    float* __restrict__ stats)
{
    if (blockIdx.x == 0 && threadIdx.x < 128) stats[threadIdx.x] = 0.f;
    int i = blockIdx.x*256 + threadIdx.x;
    if (i < 18432) {                           // wmf: 4*64*36*2
        int j   = i & 1;
        int t2  = i >> 1;
        int kb  = t2 % 36;
        int rl  = t2 / 36;
        int l   = rl & 63;
        int r   = rl >> 6;
        int row = l & 15, ksel = l >> 4;
        int och = r*16 + row;
        int P   = kb*8 + ksel*2 + j;           // 0..287
        int kt  = P >> 5;
        int cp  = P & 31;
        float lo = mw[och*576 + (2*cp    )*9 + kt];
        float hi = mw[och*576 + (2*cp + 1)*9 + kt];
        wmf[i] = pk2u(lo, hi);
    } else if (i < 36864) {                    // wof: 2*64*72*2
        int idx = i - 18432;
        int j   = idx & 1;
        int t2  = idx >> 1;
        int kb  = t2 % 72;
        int rl  = t2 / 72;
        int l   = rl & 63;
        int mt  = rl >> 6;
        int row = l & 15, ksel = l >> 4;
        int och = mt*16 + row;
        int P   = kb*8 + ksel*2 + j;           // 0..575
        int kt  = P >> 6;                      // tap 0..8
        int cp  = P & 63;                      // concat pair
        unsigned v = 0;
        if (och < 27) {
            float lo = ow[(och*128 + 2*cp    )*9 + kt];
            float hi = ow[(och*128 + 2*cp + 1)*9 + kt];
            v = pk2u(lo, hi);
        }
        wof[idx] = v;
    }
}

// ---------------- K1: offset conv via MFMA. block = quarter-row (32 px),
// 4 waves = 2 M-tiles x 2 px-tiles; K = 576 pairs in 3 tap-row chunks.
__global__ __launch_bounds__(256) void k1_offset_conv(
    const unsigned* __restrict__ f13t, const unsigned* __restrict__ wof,
    const float* __restrict__ ob, float* __restrict__ om)
{
    __shared__ unsigned tile[34*68];

    int blk = blockIdx.x;        // b(2) y(7) xq(2)
    int xq = blk & 3;
    int y  = (blk >> 2) & 127;
    int b  = blk >> 9;

    int tid  = threadIdx.x;
    int lane = tid & 63;
    int wv   = tid >> 6;
    int mt   = wv >> 1;          // M-tile (out-ch 16*mt..)
    int pxt  = wv & 1;           // px-tile
    int row  = lane & 15;
    int ksel = lane >> 4;

    f32x4 acc = {0.f, 0.f, 0.f, 0.f};
    const unsigned* wbase = wof + (size_t)(mt*64 + lane)*144;

#pragma unroll 1
    for (int dy = 0; dy < 3; ++dy) {
        int yy = y + dy - 1;
        bool yok = (unsigned)yy < (unsigned)HH;
        __syncthreads();
        for (int i = tid; i < 544; i += 256) {
            int px34 = i >> 4, q = i & 15;
            int gxp = xq*32 - 1 + px34;
            uint4 v = make_uint4(0u, 0u, 0u, 0u);
            if (yok && (unsigned)gxp < (unsigned)WW)
                v = *(const uint4*)&f13t[(((size_t)(b*128 + yy))*128 + gxp)*64 + q*4];
            *(uint4*)&tile[px34*68 + q*4] = v;
        }
        __syncthreads();

#pragma unroll
        for (int hf = 0; hf < 2; ++hf) {
            uint4 wq[6];
#pragma unroll
            for (int m = 0; m < 6; ++m)
                wq[m] = *(const uint4*)&wbase[dy*48 + hf*24 + m*4];
#pragma unroll
            for (int kl = 0; kl < 12; ++kl) {
                int Pl  = (hf*12 + kl)*8 + ksel*2;
                int ktl = Pl >> 6;
                int cp  = Pl & 63;
                U2H wa;
                uint4 q = wq[kl >> 1];
                if (kl & 1) { wa.u.x = q.z; wa.u.y = q.w; }
                else        { wa.u.x = q.x; wa.u.y = q.y; }
                U2H bfr;
                bfr.u = *(const uint2*)&tile[(pxt*16 + row + ktl)*68 + cp];
                acc = __builtin_amdgcn_mfma_f32_16x16x16f16(wa.h, bfr.h, acc, 0, 0, 0);
            }
        }
    }

    int gx = xq*32 + pxt*16 + row;
#pragma unroll
    for (int rI = 0; rI < 4; ++rI) {
        int och = mt*16 + ksel*4 + rI;
        if (och < 27) {
            float v = acc[rI] + ob[och];
            if (och >= 18) v = 1.f / (1.f + __expf(-v));   // mask sigmoid
            om[((b*27 + och) << 14) + (y << 7) + gx] = v;
        }
    }
}

// ---------------- K2: deformable conv, pk_fma_f16 phase A + b128 phase B,
// fused per-channel stats via atomics.
// block = quarter-row (32 px), 4 waves; grid 2048.
// sl layout Q-permuted: std pair P -> pos = (P>>4)*16 + ((P&7)>>1)*4
//   + ((P>>3)&1)*2 + (P&1)  [per 96-pair third, stride 100].
// LDS: params 864 + sl[32][100] = 16,256 B.
__global__ __launch_bounds__(256) void k2_deform(
    const unsigned* __restrict__ f13t, const unsigned* __restrict__ wmf,
    const float* __restrict__ om, float* __restrict__ aligned,
    float* __restrict__ stats)
{
    extern __shared__ unsigned lds[];
    unsigned* pl_a = lds;            // [9][32] addr|dx<<14|dy<<15
    unsigned* pl_w = lds + 288;      // [9][32] x uint2
    unsigned* sl   = lds + 864;      // [32 px][100]

    int blk = blockIdx.x;        // b(2) y(7) xq(2)
    int xq = blk & 3;
    int y  = (blk >> 2) & 127;
    int b  = blk >> 9;

    int tid  = threadIdx.x;
    int lane = tid & 63;
    int wv   = tid >> 6;
    int row  = lane & 15;
    int ksel = lane >> 4;
    int chg8 = lane & 7;         // phase-A: 4 pairs (16 channels... 4 u32) per lane
    int ig8  = lane >> 3;        // phase-A item subgroup 0..7

    const float* omb = om + ((b*27) << 14) + (y << 7);
    const unsigned* ftb = f13t + (((size_t)b) << 20);

    // ---- param pre-phase: 288 items (k, px)
    for (int i = tid; i < 288; i += 256) {
        int k = i >> 5, lpx = i & 31;
        int gxp = xq*32 + lpx;
        float off0 = omb[((2*k)   << 14) + gxp];
        float off1 = omb[((2*k+1) << 14) + gxp];
        float mk   = omb[((18+k)  << 14) + gxp];   // sigmoided in K1

        float pyf = (float)y   + (float)(k/3) - 1.f + off0;
        float pxg = (float)gxp + (float)(k%3) - 1.f + off1;
        float fy = floorf(pyf), fx = floorf(pxg);
        int y0 = (int)fy, x0 = (int)fx;
        float wy = pyf - fy, wx = pxg - fx;
        float oy = 1.f - wy, ox = 1.f - wx;
        bool yv0 = (unsigned)y0     < (unsigned)HH;
        bool yv1 = (unsigned)(y0+1) < (unsigned)HH;
        bool xv0 = (unsigned)x0     < (unsigned)WW;
        bool xv1 = (unsigned)(x0+1) < (unsigned)WW;
        int y0c = min(max(y0, 0), 127);
        int x0c = min(max(x0, 0), 127);
        int dy = min(max(y0+1, 0), 127) - y0c;   // 0 or 1
        int dx = min(max(x0+1, 0), 127) - x0c;   // 0 or 1
        unsigned a = (unsigned)((y0c << 7) + x0c) | ((unsigned)dx << 14) | ((unsigned)dy << 15);
        float w00 = (yv0 && xv0) ? oy*ox*mk : 0.f;
        float w01 = (yv0 && xv1) ? oy*wx*mk : 0.f;
        float w10 = (yv1 && xv0) ? wy*ox*mk : 0.f;
        float w11 = (yv1 && xv1) ? wy*wx*mk : 0.f;
        pl_a[i] = a;
        pl_w[i*2]     = pk2u(w00, w01);
        pl_w[i*2 + 1] = pk2u(w10, w11);
    }
    __syncthreads();

    f32x4 acc0 = {0.f, 0.f, 0.f, 0.f};
    f32x4 acc1 = {0.f, 0.f, 0.f, 0.f};

    const unsigned* wbase = wmf + (wv*64 + lane)*72;
    // writer position base (lane-constant part)
    int wrb = ((chg8 >> 2) << 4) + ((chg8 & 1) << 3) + (((chg8 >> 1) & 1) << 1);
    int ldcol = chg8 * 4;
    int px  = wv*8 + ig8;        // phase-A pixel (same for all 3 passes)

#pragma unroll 1
    for (int th = 0; th < 3; ++th) {
        // phase A: 3 passes; 8-lane group = one (ktl,px) item; lane does 4 pairs
#pragma unroll
        for (int it = 0; it < 3; ++it) {
            int k    = th*3 + it;
            int pidx = k*32 + px;
            unsigned a = pl_a[pidx];
            uint2 wpk = *(const uint2*)&pl_w[pidx*2];
            int i00 = (int)(a & 0x3FFFu);
            int dx  = (int)((a >> 14) & 1u);
            int i10 = i00 + (((int)(a >> 15) & 1) << 7);
            h2 hw01 = u2h(wpk.x), hw23 = u2h(wpk.y);
            h2 w00d = {hw01.x, hw01.x}, w01d = {hw01.y, hw01.y};
            h2 w10d = {hw23.x, hw23.x}, w11d = {hw23.y, hw23.y};

            uint4 t00 = *(const uint4*)&ftb[(size_t)(i00     )*64 + ldcol];
            uint4 t01 = *(const uint4*)&ftb[(size_t)(i00 + dx)*64 + ldcol];
            uint4 t10 = *(const uint4*)&ftb[(size_t)(i10     )*64 + ldcol];
            uint4 t11 = *(const uint4*)&ftb[(size_t)(i10 + dx)*64 + ldcol];

            h2 v0 = u2h(t00.x)*w00d + u2h(t01.x)*w01d + u2h(t10.x)*w10d + u2h(t11.x)*w11d;
            h2 v1 = u2h(t00.y)*w00d + u2h(t01.y)*w01d + u2h(t10.y)*w10d + u2h(t11.y)*w11d;
            h2 v2 = u2h(t00.z)*w00d + u2h(t01.z)*w01d + u2h(t10.z)*w10d + u2h(t11.z)*w11d;
            h2 v3 = u2h(t00.w)*w00d + u2h(t01.w)*w01d + u2h(t10.w)*w10d + u2h(t11.w)*w11d;

            int bs = px*100 + it*32 + wrb;
            *(uint2*)&sl[bs]     = make_uint2(h2u(v0), h2u(v1));
            *(uint2*)&sl[bs + 4] = make_uint2(h2u(v2), h2u(v3));
        }
        __syncthreads();

        // A-fragments for this third (loaded after phase A to cap VGPR)
        uint4 wq[6];
#pragma unroll
        for (int m = 0; m < 6; ++m)
            wq[m] = *(const uint4*)&wbase[th*24 + m*4];

        // phase B: 6 double-K-blocks x 2 px-tiles, b128 reads
        const unsigned* b0p = &sl[(row     )*100 + ksel*4];
        const unsigned* b1p = &sl[(16+row  )*100 + ksel*4];
#pragma unroll
        for (int m = 0; m < 6; ++m) {
            uint4 bv0 = *(const uint4*)&b0p[m*16];
            uint4 bv1 = *(const uint4*)&b1p[m*16];
            U2H waA, waB, s0a, s0b, s1a, s1b;
            waA.u.x = wq[m].x; waA.u.y = wq[m].y;
            waB.u.x = wq[m].z; waB.u.y = wq[m].w;
            s0a.u.x = bv0.x; s0a.u.y = bv0.y;
            s0b.u.x = bv0.z; s0b.u.y = bv0.w;
            s1a.u.x = bv1.x; s1a.u.y = bv1.y;
            s1b.u.x = bv1.z; s1b.u.y = bv1.w;
            acc0 = __builtin_amdgcn_mfma_f32_16x16x16f16(waA.h, s0a.h, acc0, 0, 0, 0);
            acc0 = __builtin_amdgcn_mfma_f32_16x16x16f16(waB.h, s0b.h, acc0, 0, 0, 0);
            acc1 = __builtin_amdgcn_mfma_f32_16x16x16f16(waA.h, s1a.h, acc1, 0, 0, 0);
            acc1 = __builtin_amdgcn_mfma_f32_16x16x16f16(waB.h, s1b.h, acc1, 0, 0, 0);
        }
        __syncthreads();
    }

    // write aligned + fused per-channel stats (sum, sumsq over this block's 32 px)
    int obase = ((b*CC) << 14) + (y << 7) + xq*32;
#pragma unroll
    for (int rI = 0; rI < 4; ++rI) {
        int och = wv*16 + ksel*4 + rI;
        float v0 = acc0[rI], v1 = acc1[rI];
        aligned[obase + (och << 14) + row]      = v0;
        aligned[obase + (och << 14) + 16 + row] = v1;
        float s  = v0 + v1;
        float sq = v0*v0 + v1*v1;
#pragma unroll
        for (int off = 1; off < 16; off <<= 1) {
            s  += __shfl_xor(s,  off, 64);
            sq += __shfl_xor(sq, off, 64);
        }
        if (row == 0) {
            atomicAdd(&stats[och],      s);
            atomicAdd(&stats[64 + och], sq);
        }
    }
}

// ---------------- K4: in-place normalize + affine (stats from k2 atomics)
__global__ __launch_bounds__(256) void k4_norm(
    float* __restrict__ a, const float* __restrict__ stats,
    const float* __restrict__ gamma, const float* __restrict__ beta)
{
    const float invN = 1.f / 65536.f;
    int n4 = (BB*CC*HWP) / 4;
    for (int i4 = blockIdx.x*256 + threadIdx.x; i4 < n4; i4 += gridDim.x*256) {
        int c = (i4 >> 12) & 63;
        float mean = stats[c] * invN;
        float var  = stats[64 + c] * invN - mean*mean;
        float sc = gamma[c] * rsqrtf(var + 1e-5f);
        float sh = beta[c] - mean*sc;
        float4 v = ((const float4*)a)[i4];
        v.x = v.x*sc + sh; v.y = v.y*sc + sh;
        v.z = v.z*sc + sh; v.w = v.w*sc + sh;
        ((float4*)a)[i4] = v;
    }
}

extern "C" void kernel_launch(void* const* d_in, const int* in_sizes, int n_in,
                              void* d_out, int out_size, void* d_ws, size_t ws_size,
                              hipStream_t stream)
{
    const float* f1    = (const float*)d_in[0];
    const float* f3    = (const float*)d_in[1];
    const float* ow    = (const float*)d_in[2];
    const float* ob    = (const float*)d_in[3];
    const float* mw    = (const float*)d_in[4];
    const float* gamma = (const float*)d_in[5];
    const float* beta  = (const float*)d_in[6];
    float* out = (float*)d_out;

    float* om     = (float*)d_ws;                 // [4][27][128][128] = 7,077,888 B
    float* stats  = om + 4*27*HWP;                // [128] floats
    unsigned* wmf = (unsigned*)(stats + 512);     // 18432 u32
    unsigned* wof = wmf + 18432;                  // 18432 u32
    unsigned* f13t = wof + 18432;                 // [4][128][128][64] u32 = 16 MB

    const int lds2 = (864 + 32*100) * 4;          // 16,256 B
    (void)hipFuncSetAttribute((const void*)k2_deform,
        hipFuncAttributeMaxDynamicSharedMemorySize, lds2);

    hipLaunchKernelGGL(k0_wt, dim3(144), dim3(256), 0, stream, ow, mw, wmf, wof, stats);
    hipLaunchKernelGGL(kT, dim3(512), dim3(256), 0, stream, f1, f3, f13t);
    hipLaunchKernelGGL(k1_offset_conv, dim3(2048), dim3(256), 0, stream,
                       f13t, wof, ob, om);
    hipLaunchKernelGGL(k2_deform, dim3(2048), dim3(256), lds2, stream,
                       f13t, wmf, om, out, stats);
    hipLaunchKernelGGL(k4_norm, dim3(2048), dim3(256), 0, stream,
                       out, stats, gamma, beta);
}